// Round 14
// baseline (90151.068 us; speedup 1.0000x reference)
//
#include <hip/hip_runtime.h>

#define B_ 32
#define S_ 512
#define E_ 256
#define H_ 512
#define G_ 2048
#define K_ 7
#define SCOPE __HIP_MEMORY_SCOPE_AGENT

__device__ __forceinline__ float sigm(float x) { return 1.f / (1.f + expf(-x)); }

__device__ __forceinline__ float ldc(const float* p) {
    return __hip_atomic_load(p, __ATOMIC_RELAXED, SCOPE);
}
__device__ __forceinline__ void ld2c(const float* p, float& a, float& b) {
    unsigned long long v =
        __hip_atomic_load((const unsigned long long*)p, __ATOMIC_RELAXED, SCOPE);
    a = __builtin_bit_cast(float, (unsigned)v);
    b = __builtin_bit_cast(float, (unsigned)(v >> 32));
}
__device__ __forceinline__ void stg(float* p, float v) {
    __hip_atomic_store(p, v, __ATOMIC_RELAXED, SCOPE);
}

// 2-level monotonic grid barrier (validated round 9).
__device__ __forceinline__ void gbar(unsigned* bar, int tid, int wg, unsigned n) {
    __syncthreads();
    if (tid == 0) {
        int g = wg >> 5;
        unsigned* gcnt = bar + 64 + g * 32;
        unsigned* ggen = bar + 320 + g * 32;
        unsigned old = __hip_atomic_fetch_add(gcnt, 1u, __ATOMIC_RELAXED, SCOPE);
        if (old == n * 32u - 1u) {
            unsigned rold = __hip_atomic_fetch_add(bar, 1u, __ATOMIC_RELAXED, SCOPE);
            if (rold == n * 8u - 1u) {
                __hip_atomic_store(bar + 32, n, __ATOMIC_RELAXED, SCOPE);
            } else {
                while (__hip_atomic_load(bar + 32, __ATOMIC_RELAXED, SCOPE) < n)
                    __builtin_amdgcn_s_sleep(1);
            }
            __hip_atomic_store(ggen, n, __ATOMIC_RELAXED, SCOPE);
        } else {
            while (__hip_atomic_load(ggen, __ATOMIC_RELAXED, SCOPE) < n)
                __builtin_amdgcn_s_sleep(1);
        }
        asm volatile("" ::: "memory");
    }
    __syncthreads();
}

#define REP16(M) M(0) M(1) M(2) M(3) M(4) M(5) M(6) M(7) \
                 M(8) M(9) M(10) M(11) M(12) M(13) M(14) M(15)
#define REP32(M) REP16(M) M(16) M(17) M(18) M(19) M(20) M(21) M(22) M(23) \
                 M(24) M(25) M(26) M(27) M(28) M(29) M(30) M(31)

// ---------------- Phase A macros: chunked register-prefetch weight stream ----
// row(j) = j*16+rc ; j<16 -> PA0 (first 256 rows), j>=16 -> PA1 (next 512 rows)
#define WROW(j) ((j) < 16 ? PA0 + (size_t)((j) * 16 + rc) * ldA \
                          : PA1 + (size_t)(((j) - 16) * 16 + rc) * ldA)
#define LDW8(c, P) \
    P##0 = *(const float2*)WROW((c)*8+0); P##1 = *(const float2*)WROW((c)*8+1); \
    P##2 = *(const float2*)WROW((c)*8+2); P##3 = *(const float2*)WROW((c)*8+3); \
    P##4 = *(const float2*)WROW((c)*8+4); P##5 = *(const float2*)WROW((c)*8+5); \
    P##6 = *(const float2*)WROW((c)*8+6); P##7 = *(const float2*)WROW((c)*8+7);
#define FMA1(W, AV, bg) \
    A0_##bg.x = fmaf(W.x, AV.x, A0_##bg.x); A0_##bg.y = fmaf(W.x, AV.y, A0_##bg.y); \
    A0_##bg.z = fmaf(W.x, AV.z, A0_##bg.z); A0_##bg.w = fmaf(W.x, AV.w, A0_##bg.w); \
    A1_##bg.x = fmaf(W.y, AV.x, A1_##bg.x); A1_##bg.y = fmaf(W.y, AV.y, A1_##bg.y); \
    A1_##bg.z = fmaf(W.y, AV.z, A1_##bg.z); A1_##bg.w = fmaf(W.y, AV.w, A1_##bg.w);
#define FMAROW(W, j) { \
    const float* ar_ = sact + ((j) * 16 + rc) * 36; \
    { float4 av_ = *(const float4*)(ar_ +  0); FMA1(W, av_, 0) } \
    { float4 av_ = *(const float4*)(ar_ +  4); FMA1(W, av_, 1) } \
    { float4 av_ = *(const float4*)(ar_ +  8); FMA1(W, av_, 2) } \
    { float4 av_ = *(const float4*)(ar_ + 12); FMA1(W, av_, 3) } \
    { float4 av_ = *(const float4*)(ar_ + 16); FMA1(W, av_, 4) } \
    { float4 av_ = *(const float4*)(ar_ + 20); FMA1(W, av_, 5) } \
    { float4 av_ = *(const float4*)(ar_ + 24); FMA1(W, av_, 6) } \
    { float4 av_ = *(const float4*)(ar_ + 28); FMA1(W, av_, 7) } }
#define CHUNK(c, P) \
    FMAROW(P##0, (c)*8+0) FMAROW(P##1, (c)*8+1) FMAROW(P##2, (c)*8+2) \
    FMAROW(P##3, (c)*8+3) FMAROW(P##4, (c)*8+4) FMAROW(P##5, (c)*8+5) \
    FMAROW(P##6, (c)*8+6) FMAROW(P##7, (c)*8+7)
#define DECL_ACC(bg) float4 A0_##bg = {0,0,0,0}; float4 A1_##bg = {0,0,0,0};
#define RED1(v) v += __shfl_xor(v, 4, 64); v += __shfl_xor(v, 8, 64); \
                v += __shfl_xor(v, 16, 64); v += __shfl_xor(v, 32, 64);
#define RED4(F) RED1(F.x) RED1(F.y) RED1(F.z) RED1(F.w)
#define REDBG(bg) RED4(A0_##bg) RED4(A1_##bg)
#define WOUT(bg) \
    smisc[(4*(bg)+0)*64+tc] = A0_##bg.x; smisc[(4*(bg)+0)*64+tc+1] = A1_##bg.x; \
    smisc[(4*(bg)+1)*64+tc] = A0_##bg.y; smisc[(4*(bg)+1)*64+tc+1] = A1_##bg.y; \
    smisc[(4*(bg)+2)*64+tc] = A0_##bg.z; smisc[(4*(bg)+2)*64+tc+1] = A1_##bg.z; \
    smisc[(4*(bg)+3)*64+tc] = A0_##bg.w; smisc[(4*(bg)+3)*64+tc+1] = A1_##bg.w;
#define REPBG(M) M(0) M(1) M(2) M(3) M(4) M(5) M(6) M(7)

// Phase B weights: fresh per step, burst-issued before staging
#define DECLB(i) float wB##i;
#define LDWB(i) wB##i = Ws_p1[(size_t)colB * 512 + (i) * 16 + rcB];
#define FMAB(i) { float4 av = *(const float4*)(ap2 + (i) * 576); \
    c0 = fmaf(wB##i, av.x, c0); c1 = fmaf(wB##i, av.y, c1); \
    c2 = fmaf(wB##i, av.z, c2); c3 = fmaf(wB##i, av.w, c3); }

__global__ __launch_bounds__(512, 2) void fused_all(
        const int* __restrict__ x, const int* __restrict__ taskp,
        const float* __restrict__ embed,
        const float* __restrict__ Wx_t, const float* __restrict__ Wh_t,
        const float* __restrict__ b_t,
        const float* __restrict__ Ws_p1, const float* __restrict__ Ws_p2,
        const float* __restrict__ Us_w,
        const float* __restrict__ Wx_c, const float* __restrict__ Wh_c,
        const float* __restrict__ Wm_c, const float* __restrict__ b_c,
        float* __restrict__ out,
        float* __restrict__ emb_t,
        float* __restrict__ h_task, float* __restrict__ c_task,
        float* __restrict__ h_main, float* __restrict__ c_main,
        float* __restrict__ p2w, float* __restrict__ partial,
        unsigned* __restrict__ bar)
{
    __shared__ float sact[27648];   // A: [768][36]; B: [512][36]; C: [1280][4]
    __shared__ float smisc[2048];

    const int wg = blockIdx.x, tid = threadIdx.x;
    const int lane = tid & 63, wave = tid >> 6;
    const int task = taskp[0];
    unsigned bn = 0;

    const int cp = wave * 4 + (lane & 3);
    const int rc = (lane >> 2) & 15;
    const int tc = 2 * cp;

    // ---------------- prologue: zero state, emb gather+transpose ----------------
    for (int i = wg * 512 + tid; i < 393216; i += 131072)
        stg(&h_task[i], 0.f);
    for (int w = wg * 2 + (tid >> 8); w < S_ * B_; w += 512) {
        int ts = w >> 5, b = w & 31;
        int tok = x[b * S_ + ts];
        stg(&emb_t[(size_t)ts * 8192 + (tid & 255) * 32 + b],
            embed[(size_t)tok * E_ + (tid & 255)]);
    }
    const int kA = wg >> 5, ntA = wg & 31;
    const int wcA = ((tc >> 4) << 9) + ntA * 16 + (tc & 15);
    const int cB = tid & 15, rcB = (tid >> 4) & 15, bhB = tid >> 8;
    const int colB = (wg & 31) * 16 + cB;
    gbar(bar, tid, wg, ++bn);

    for (int t = 0; t < S_; ++t) {
        const int old = t & 1, nw = old ^ 1;
        float* ht_old = h_task + (size_t)old * K_ * B_ * H_;
        float* ht_new = h_task + (size_t)nw * K_ * B_ * H_;
        float* hm_old = h_main + (size_t)old * B_ * H_;
        float* hm_new = h_main + (size_t)nw * B_ * H_;

        // ================= Phase A: task gates+cell (wg<224) + p2 (224..231) =====
        if (wg < 232) {
            const bool istask = wg < 224;
            const float* PA0; const float* PA1; size_t ldA;
            if (istask) {
                int kk = kA + (kA >= task);
                PA0 = Wx_t + (size_t)kk * 256 * 2048 + wcA;
                PA1 = Wh_t + (size_t)kk * 512 * 2048 + wcA;
                ldA = 2048;
            } else {
                int wcP = (wg - 224) * 64 + tc;
                PA0 = Ws_p2 + wcP;
                PA1 = Ws_p2 + (size_t)256 * 512 + wcP;
                ldA = 512;
            }
            float2 W0, W1, W2, W3, W4, W5, W6, W7;
            float2 V0, V1, V2, V3, V4, V5, V6, V7;
            REPBG(DECL_ACC)
            LDW8(0, W)                       // chunk 0 in flight during staging
            if (istask) {
                for (int j = 0; j < 8; ++j) {
                    int idx = tid + 512 * j;
                    int rho = idx >> 4, b2 = (idx & 15) << 1;
                    *(float2*)(sact + rho * 36 + b2) =
                        *(const float2*)(emb_t + (size_t)t * 8192 + rho * 32 + b2);
                }
                for (int j = 0; j < 16; ++j) {
                    int idx = tid + 512 * j;
                    int b = idx & 31, rp = idx >> 5;
                    float va, vb;
                    ld2c(&ht_old[((size_t)kA * 32 + b) * 512 + 2 * rp], va, vb);
                    sact[(256 + 2 * rp) * 36 + b] = va;
                    sact[(257 + 2 * rp) * 36 + b] = vb;
                }
            } else {
                for (int j = 0; j < 16; ++j) {
                    int idx = tid + 512 * j;
                    int b = idx & 31, rp = idx >> 5;
                    float va, vb;
                    ld2c(&hm_old[(size_t)b * 512 + 2 * rp], va, vb);
                    sact[(2 * rp) * 36 + b] = va;
                    sact[(2 * rp + 1) * 36 + b] = vb;
                }
                for (int j = 0; j < 8; ++j) {
                    int idx = tid + 512 * j;
                    int rho = idx >> 4, b2 = (idx & 15) << 1;
                    *(float2*)(sact + (512 + rho) * 36 + b2) =
                        *(const float2*)(emb_t + (size_t)t * 8192 + rho * 32 + b2);
                }
            }
            LDW8(1, V)                       // chunk 1 in flight across barrier
            __syncthreads();
            CHUNK(0, W) LDW8(2, W)           // prefetch c+2 while computing c+1
            CHUNK(1, V) LDW8(3, V)
            CHUNK(2, W) LDW8(4, W)
            CHUNK(3, V) LDW8(5, V)
            CHUNK(4, W)
            CHUNK(5, V)
            REPBG(REDBG)
            if (rc == 0) { REPBG(WOUT) }
            __syncthreads();
            if (istask) {
                int kk = kA + (kA >= task);
                int b = tid >> 4, hc = tid & 15;
                const float* bb = b_t + kk * G_ + ntA * 16 + hc;
                float gi = smisc[b * 64 + hc]      + bb[0];
                float gf = smisc[b * 64 + 16 + hc] + bb[512];
                float gg = smisc[b * 64 + 32 + hc] + bb[1024];
                float go = smisc[b * 64 + 48 + hc] + bb[1536];
                size_t cidx = ((size_t)kA * 32 + b) * 512 + ntA * 16 + hc;
                float cold = c_task[cidx];
                float cn = sigm(gf) * cold + sigm(gi) * tanhf(gg);
                float hn = sigm(go) * tanhf(cn);
                c_task[cidx] = cn;
                stg(&ht_new[cidx], hn);
            } else {
                int pb = wg - 224;
                for (int j = 0; j < 4; ++j) {
                    int idx = tid + 512 * j;
                    int b = idx >> 6, col = idx & 63;
                    stg(&p2w[(size_t)b * 512 + pb * 64 + col], smisc[b * 64 + col]);
                }
            }
        }
        gbar(bar, tid, wg, ++bn);

        // ================= Phase B: attention partials (wg<224) =================
        if (wg < 224) {
            const int ktB = wg >> 5, itB = wg & 31;
            REP32(DECLB)
            REP32(LDWB)                      // burst-issued; latency hides under staging
            for (int j = 0; j < 16; ++j) {
                int idx = tid + 512 * j;
                int b = idx & 31, rp = idx >> 5;
                float va, vb;
                ld2c(&ht_new[((size_t)ktB * 32 + b) * 512 + 2 * rp], va, vb);
                sact[(2 * rp) * 36 + b] = va;
                sact[(2 * rp + 1) * 36 + b] = vb;
            }
            __syncthreads();
            for (int bg = 0; bg < 4; ++bg) {
                float c0 = 0, c1 = 0, c2 = 0, c3 = 0;
                const float* ap2 = sact + rcB * 36 + bhB * 16 + 4 * bg;
                REP32(FMAB)
                c0 += __shfl_xor(c0, 16, 64); c0 += __shfl_xor(c0, 32, 64);
                c1 += __shfl_xor(c1, 16, 64); c1 += __shfl_xor(c1, 32, 64);
                c2 += __shfl_xor(c2, 16, 64); c2 += __shfl_xor(c2, 32, 64);
                c3 += __shfl_xor(c3, 16, 64); c3 += __shfl_xor(c3, 32, 64);
                if ((rcB & 3) == 0) {
                    int pp = rcB >> 2;
                    int bb0 = bhB * 16 + bg * 4;
                    smisc[pp * 512 + (bb0 + 0) * 16 + cB] = c0;
                    smisc[pp * 512 + (bb0 + 1) * 16 + cB] = c1;
                    smisc[pp * 512 + (bb0 + 2) * 16 + cB] = c2;
                    smisc[pp * 512 + (bb0 + 3) * 16 + cB] = c3;
                }
            }
            __syncthreads();
            {
                int b = tid >> 4, c = tid & 15;
                float s = smisc[b * 16 + c] + smisc[512 + b * 16 + c]
                        + smisc[1024 + b * 16 + c] + smisc[1536 + b * 16 + c];
                s = tanhf(s + ldc(&p2w[(size_t)b * 512 + itB * 16 + c]))
                    * Us_w[itB * 16 + c];
                s += __shfl_xor(s, 1, 64); s += __shfl_xor(s, 2, 64);
                s += __shfl_xor(s, 4, 64); s += __shfl_xor(s, 8, 64);
                if (c == 0) stg(&partial[((size_t)ktB * 32 + itB) * 32 + b], s);
            }
        }
        gbar(bar, tid, wg, ++bn);

        // ================= Phase C: softmax + Rt + main gates + cell ============
        {
            const int ntC = ((wg >> 6) << 3) + (wg & 7);
            const int btC = (wg >> 3) & 7;
            const int wcC = ((tc >> 4) << 9) + ntC * 16 + (tc & 15);
            float* ssi = smisc;
            float* sa  = smisc + 32;
            float* sgt = smisc + 64;
            if (tid < 28) {
                int kq = tid >> 2, b2 = tid & 3;
                float ssum = 0.f;
                for (int itq = 0; itq < 32; ++itq)
                    ssum += ldc(&partial[((size_t)kq * 32 + itq) * 32 + 4 * btC + b2]);
                ssi[b2 * 7 + kq] = ssum;
            }
            __syncthreads();
            if (tid < 4) {
                float mx = -1e30f;
                for (int kq = 0; kq < 7; ++kq) mx = fmaxf(mx, ssi[tid * 7 + kq]);
                float den = 0.f, e[7];
                for (int kq = 0; kq < 7; ++kq) { e[kq] = expf(ssi[tid * 7 + kq] - mx); den += e[kq]; }
                float rd = 1.f / den;
                for (int kq = 0; kq < 7; ++kq) sa[tid * 7 + kq] = e[kq] * rd;
            }
            if (tid < 256)
                *(float4*)(sact + tid * 4) =
                    *(const float4*)(emb_t + (size_t)t * 8192 + tid * 32 + 4 * btC);
            for (int j = 0; j < 2; ++j) {
                int idx = tid + 512 * j;
                int bl = idx & 3, rp = idx >> 2;
                float va, vb;
                ld2c(&hm_old[(size_t)(4 * btC + bl) * 512 + 2 * rp], va, vb);
                sact[(256 + 2 * rp) * 4 + bl] = va;
                sact[(257 + 2 * rp) * 4 + bl] = vb;
            }
            __syncthreads();
            for (int j = 0; j < 2; ++j) {
                int idx = tid + 512 * j;
                int bl = idx & 3, rp = idx >> 2;
                float v0 = 0.f, v1 = 0.f;
#pragma unroll
                for (int kq = 0; kq < 7; ++kq) {
                    float ha, hb;
                    ld2c(&ht_new[((size_t)kq * 32 + 4 * btC + bl) * 512 + 2 * rp], ha, hb);
                    float aq = sa[bl * 7 + kq];
                    v0 = fmaf(aq, ha, v0);
                    v1 = fmaf(aq, hb, v1);
                }
                sact[(768 + 2 * rp) * 4 + bl] = v0;
                sact[(769 + 2 * rp) * 4 + bl] = v1;
            }
            __syncthreads();
            float a00 = 0, a01 = 0, a02 = 0, a03 = 0;
            float a10 = 0, a11 = 0, a12 = 0, a13 = 0;
            const float* ap = sact + rc * 4;
#pragma unroll
            for (int i = 0; i < 80; ++i) {
                int row = i * 16 + rc;
                const float* wsrc = (i < 16)
                    ? (Wx_c + (size_t)row * 2048 + wcC)
                    : (i < 48) ? (Wh_c + (size_t)(row - 256) * 2048 + wcC)
                               : (Wm_c + (size_t)(row - 768) * 2048 + wcC);
                float2 w = *(const float2*)wsrc;
                float4 av = *(const float4*)(ap + i * 64);
                a00 = fmaf(w.x, av.x, a00); a01 = fmaf(w.x, av.y, a01);
                a02 = fmaf(w.x, av.z, a02); a03 = fmaf(w.x, av.w, a03);
                a10 = fmaf(w.y, av.x, a10); a11 = fmaf(w.y, av.y, a11);
                a12 = fmaf(w.y, av.z, a12); a13 = fmaf(w.y, av.w, a13);
            }
            RED1(a00) RED1(a01) RED1(a02) RED1(a03)
            RED1(a10) RED1(a11) RED1(a12) RED1(a13)
            if (rc == 0) {
                sgt[0 * 64 + tc] = a00; sgt[0 * 64 + tc + 1] = a10;
                sgt[1 * 64 + tc] = a01; sgt[1 * 64 + tc + 1] = a11;
                sgt[2 * 64 + tc] = a02; sgt[2 * 64 + tc + 1] = a12;
                sgt[3 * 64 + tc] = a03; sgt[3 * 64 + tc + 1] = a13;
            }
            __syncthreads();
            if (tid < 64) {
                int bl = tid >> 4, hc = tid & 15;
                int gb = 4 * btC + bl;
                float g4[4];
#pragma unroll
                for (int g = 0; g < 4; ++g)
                    g4[g] = sgt[bl * 64 + g * 16 + hc] + b_c[g * 512 + ntC * 16 + hc];
                size_t cidx = (size_t)gb * 512 + ntC * 16 + hc;
                float cold = c_main[cidx];
                float cn = sigm(g4[1]) * cold + sigm(g4[0]) * tanhf(g4[2]);
                float hn = sigm(g4[3]) * tanhf(cn);
                c_main[cidx] = cn;
                stg(&hm_new[cidx], hn);
                out[(size_t)gb * S_ * H_ + (size_t)t * 512 + ntC * 16 + hc] = hn;
            }
        }
        gbar(bar, tid, wg, ++bn);
    }

    for (int i = wg * 512 + tid; i < B_ * H_; i += 131072)
        out[(size_t)B_ * S_ * H_ + i] = ldc(&h_main[i]);
}

extern "C" void kernel_launch(void* const* d_in, const int* in_sizes, int n_in,
                              void* d_out, int out_size, void* d_ws, size_t ws_size,
                              hipStream_t stream) {
    const int*   x      = (const int*)d_in[0];
    const int*   taskp  = (const int*)d_in[1];
    const float* embed  = (const float*)d_in[2];
    const float* Wx_t   = (const float*)d_in[3];
    const float* Wh_t   = (const float*)d_in[4];
    const float* b_t    = (const float*)d_in[5];
    const float* Ws_p1  = (const float*)d_in[6];
    const float* Ws_p2  = (const float*)d_in[7];
    const float* Us_w   = (const float*)d_in[8];
    const float* Wx_c   = (const float*)d_in[10];
    const float* Wh_c   = (const float*)d_in[11];
    const float* Wm_c   = (const float*)d_in[12];
    const float* b_c    = (const float*)d_in[13];
    float* out = (float*)d_out;

    float* ws = (float*)d_ws;
    float* emb_t   = ws;                                  // S*E*B   = 4,194,304 ([t][e][b])
    float* h_task  = emb_t   + (size_t)S_ * E_ * B_;      // 2*K*B*H =   229,376
    float* c_task  = h_task  + 2 * (size_t)K_ * B_ * H_;  // K*B*H   =   114,688
    float* h_main  = c_task  + (size_t)K_ * B_ * H_;      // 2*B*H   =    32,768
    float* c_main  = h_main  + 2 * (size_t)B_ * H_;       // B*H     =    16,384
    float* p2      = c_main  + (size_t)B_ * H_;           // B*H     =    16,384
    float* partial = p2      + (size_t)B_ * H_;           // K*32*32 =     7,168
    unsigned* bar  = (unsigned*)(partial + 7168);         // 2-level barrier state

    hipMemsetAsync(bar, 0, 4096, stream);

    void* args[] = { (void*)&x, (void*)&taskp, (void*)&embed,
                     (void*)&Wx_t, (void*)&Wh_t, (void*)&b_t,
                     (void*)&Ws_p1, (void*)&Ws_p2, (void*)&Us_w,
                     (void*)&Wx_c, (void*)&Wh_c, (void*)&Wm_c, (void*)&b_c,
                     (void*)&out,
                     (void*)&emb_t, (void*)&h_task, (void*)&c_task,
                     (void*)&h_main, (void*)&c_main, (void*)&p2, (void*)&partial,
                     (void*)&bar };
    hipLaunchCooperativeKernel((void*)fused_all, dim3(256), dim3(512), args, 0, stream);
}

// Round 15
// 16125.566 us; speedup vs baseline: 5.5906x; 5.5906x over previous
//
#include <hip/hip_runtime.h>

#define S_ 512
#define SCOPE __HIP_MEMORY_SCOPE_AGENT

typedef short bf16x8 __attribute__((ext_vector_type(8)));
typedef float f32x4 __attribute__((ext_vector_type(4)));

__device__ __forceinline__ float sigm(float x) { return 1.f / (1.f + expf(-x)); }
__device__ __forceinline__ float b2f(unsigned short u) {
    return __builtin_bit_cast(float, (unsigned)u << 16);
}
__device__ __forceinline__ unsigned short f2b(float f) {
    unsigned x = __builtin_bit_cast(unsigned, f);
    return (unsigned short)((x + 0x7fffu + ((x >> 16) & 1u)) >> 16);
}
__device__ __forceinline__ float ldcf(const float* p) {
    return __hip_atomic_load(p, __ATOMIC_RELAXED, SCOPE);
}
__device__ __forceinline__ unsigned ldc32(const void* p) {
    return __hip_atomic_load((const unsigned*)p, __ATOMIC_RELAXED, SCOPE);
}
__device__ __forceinline__ unsigned long long ldc64(const void* p) {
    return __hip_atomic_load((const unsigned long long*)p, __ATOMIC_RELAXED, SCOPE);
}
__device__ __forceinline__ void stg32(void* p, unsigned v) {
    __hip_atomic_store((unsigned*)p, v, __ATOMIC_RELAXED, SCOPE);
}
__device__ __forceinline__ void stgf(float* p, float v) {
    __hip_atomic_store(p, v, __ATOMIC_RELAXED, SCOPE);
}
// coherent bf16x8 fragment (cross-WG per-step data)
__device__ __forceinline__ bf16x8 frag_c(const unsigned short* p) {
    union { unsigned long long q[2]; bf16x8 v; } u;
    u.q[0] = ldc64(p); u.q[1] = ldc64(p + 4);
    return u.v;
}
// plain bf16x8 fragment (static data: weights, emb; LDS)
__device__ __forceinline__ bf16x8 frag_p(const unsigned short* p) {
    return *(const bf16x8*)p;
}

// 2-level monotonic grid barrier (validated round 9).
__device__ __forceinline__ void gbar(unsigned* bar, int tid, int wg, unsigned n) {
    __syncthreads();
    if (tid == 0) {
        int g = wg >> 5;
        unsigned* gcnt = bar + 64 + g * 32;
        unsigned* ggen = bar + 320 + g * 32;
        unsigned old = __hip_atomic_fetch_add(gcnt, 1u, __ATOMIC_RELAXED, SCOPE);
        if (old == n * 32u - 1u) {
            unsigned rold = __hip_atomic_fetch_add(bar, 1u, __ATOMIC_RELAXED, SCOPE);
            if (rold == n * 8u - 1u) {
                __hip_atomic_store(bar + 32, n, __ATOMIC_RELAXED, SCOPE);
            } else {
                while (__hip_atomic_load(bar + 32, __ATOMIC_RELAXED, SCOPE) < n)
                    __builtin_amdgcn_s_sleep(1);
            }
            __hip_atomic_store(ggen, n, __ATOMIC_RELAXED, SCOPE);
        } else {
            while (__hip_atomic_load(ggen, __ATOMIC_RELAXED, SCOPE) < n)
                __builtin_amdgcn_s_sleep(1);
        }
        asm volatile("" ::: "memory");
    }
    __syncthreads();
}

__global__ __launch_bounds__(512) void fused_all(
        const int* __restrict__ x, const int* __restrict__ taskp,
        const float* __restrict__ embed,
        const float* __restrict__ Wx_t, const float* __restrict__ Wh_t,
        const float* __restrict__ b_t,
        const float* __restrict__ Ws_p1, const float* __restrict__ Ws_p2,
        const float* __restrict__ Us_w,
        const float* __restrict__ Wx_c, const float* __restrict__ Wh_c,
        const float* __restrict__ Wm_c, const float* __restrict__ b_c,
        float* __restrict__ out,
        unsigned short* __restrict__ WTa,  unsigned short* __restrict__ WTp2,
        unsigned short* __restrict__ WTp1, unsigned short* __restrict__ WTc,
        unsigned short* __restrict__ embbf, unsigned short* __restrict__ hbf,
        unsigned short* __restrict__ hmbf,
        float* __restrict__ ctask, float* __restrict__ cmain,
        float* __restrict__ p2w, float* __restrict__ partial,
        float* __restrict__ hNf, unsigned* __restrict__ bar)
{
    __shared__ float smem[7168];
    const int wg = blockIdx.x, tid = threadIdx.x;
    const int lane = tid & 63, wave = tid >> 6;
    const int rowm = lane & 15, ks = lane >> 4;
    const int task = taskp[0];
    unsigned bn = 0;

    // ================= prologue: zero state + bf16 transposed weight build ======
    for (int i = wg * 512 + tid; i < 114688; i += 131072) stg32((unsigned*)hbf + i, 0u);
    for (int i = wg * 512 + tid; i < 16384; i += 131072) stg32((unsigned*)hmbf + i, 0u);
    for (int i = wg * 512 + tid; i < 114688; i += 131072) stgf(ctask + i, 0.f);
    for (int i = wg * 512 + tid; i < 16384; i += 131072) stgf(cmain + i, 0.f);
    // emb gather -> bf16 [t][b][e]
    for (int i = wg * 512 + tid; i < 2097152; i += 131072) {
        int ts = i >> 12, b = (i >> 7) & 31, ep = i & 127;
        int tok = x[b * S_ + ts];
        const float* s = embed + (size_t)tok * 256 + 2 * ep;
        stg32((unsigned*)embbf + i, (unsigned)f2b(s[0]) | ((unsigned)f2b(s[1]) << 16));
    }
    // WTa[s=(k,nt)][cg64][kr768]: col(cg)=(cg>>4)*512+nt*16+(cg&15); k-rows: Wx|Wh
    for (int i = wg * 512 + tid; i < 5505024; i += 131072) {
        int s = i / 24576, r = i % 24576, kp = r >> 6, cg = r & 63;
        int k = s >> 5, nt = s & 31, kk = k + (k >= task);
        int col = ((cg >> 4) << 9) + nt * 16 + (cg & 15);
        int kr = kp * 2;
        const float* src = (kr < 256)
            ? Wx_t + (size_t)kk * 524288 + (size_t)kr * 2048 + col
            : Wh_t + (size_t)kk * 1048576 + (size_t)(kr - 256) * 2048 + col;
        stg32((unsigned*)WTa + (size_t)s * 24576 + cg * 384 + kp,
              (unsigned)f2b(src[0]) | ((unsigned)f2b(src[2048]) << 16));
    }
    // WTp2[pb][cg64][kr768]
    for (int i = wg * 512 + tid; i < 196608; i += 131072) {
        int p = i / 24576, r = i % 24576, kp = r >> 6, cg = r & 63;
        int col = p * 64 + cg, kr = kp * 2;
        const float* src = Ws_p2 + (size_t)kr * 512 + col;
        stg32((unsigned*)WTp2 + p * 24576 + cg * 384 + kp,
              (unsigned)f2b(src[0]) | ((unsigned)f2b(src[512]) << 16));
    }
    // WTp1 = bf16(Ws_p1) [i][j]
    for (int i = wg * 512 + tid; i < 131072; i += 131072) {
        const float* src = Ws_p1 + 2 * (size_t)i;
        stg32((unsigned*)WTp1 + i, (unsigned)f2b(src[0]) | ((unsigned)f2b(src[1]) << 16));
    }
    // WTc[ntc][cg16][kr1280]: col(cg)=(cg>>2)*512+ntc*4+(cg&3); rows: Wx_c|Wh_c|Wm_c
    for (int i = wg * 512 + tid; i < 1310720; i += 131072) {
        int ntc = i / 10240, r = i % 10240, kp = r >> 4, cg = r & 15;
        int col = ((cg >> 2) << 9) + ntc * 4 + (cg & 3);
        int kr = kp * 2;
        const float* src = (kr < 256) ? Wx_c + (size_t)kr * 2048 + col
                         : (kr < 768) ? Wh_c + (size_t)(kr - 256) * 2048 + col
                                      : Wm_c + (size_t)(kr - 768) * 2048 + col;
        stg32((unsigned*)WTc + ntc * 10240 + cg * 640 + kp,
              (unsigned)f2b(src[0]) | ((unsigned)f2b(src[2048]) << 16));
    }
    gbar(bar, tid, wg, ++bn);

    for (int t = 0; t < S_; ++t) {
        const int old = t & 1, nw = old ^ 1;
        const unsigned short* hb_old = hbf + old * 114688;
        unsigned short* hb_new = hbf + nw * 114688;
        const unsigned short* hm_old = hmbf + old * 16384;
        unsigned short* hm_new = hmbf + nw * 16384;
        const unsigned short* et = embbf + (size_t)t * 8192;

        // ================= Phase A: task gates+cell (wg<224) + p2 (224..231) =====
        if (wg < 232) {
            f32x4 acc = {0.f, 0.f, 0.f, 0.f};
            if (wg < 224) {
                int k = wg >> 5, nt = wg & 31;
                int mt = wave >> 2, g = wave & 3;
                int b = mt * 16 + rowm;
                const unsigned short* wtp = WTa + (size_t)wg * 49152 + (g * 16 + rowm) * 768;
                const unsigned short* ep_ = et + b * 256;
                const unsigned short* hp_ = hb_old + (k * 32 + b) * 512;
#pragma unroll
                for (int kt = 0; kt < 24; ++kt) {
                    int ko = kt * 32 + ks * 8;
                    bf16x8 bf = frag_p(wtp + ko);
                    bf16x8 af = (kt < 8) ? frag_p(ep_ + ko) : frag_c(hp_ + ko - 256);
                    acc = __builtin_amdgcn_mfma_f32_16x16x32_bf16(af, bf, acc, 0, 0, 0);
                }
                float* sg = smem;
#pragma unroll
                for (int r2 = 0; r2 < 4; ++r2)
                    sg[(mt * 16 + (lane >> 4) * 4 + r2) * 64 + g * 16 + rowm] = acc[r2];
                __syncthreads();
                {
                    int b2 = tid >> 4, hc = tid & 15;
                    int kk = k + (k >= task);
                    const float* bb = b_t + kk * 2048 + nt * 16 + hc;
                    float gi = sg[b2 * 64 + hc]      + bb[0];
                    float gf = sg[b2 * 64 + 16 + hc] + bb[512];
                    float gg = sg[b2 * 64 + 32 + hc] + bb[1024];
                    float go = sg[b2 * 64 + 48 + hc] + bb[1536];
                    int cidx = (k * 32 + b2) * 512 + nt * 16 + hc;
                    float cold = ctask[cidx];
                    float cn = sigm(gf) * cold + sigm(gi) * tanhf(gg);
                    float hn = sigm(go) * tanhf(cn);
                    ctask[cidx] = cn;
                    int hbits = (int)f2b(hn);
                    int oth = __shfl_xor(hbits, 1, 64);
                    if ((hc & 1) == 0)
                        stg32(hb_new + cidx, (unsigned)hbits | ((unsigned)oth << 16));
                }
            } else {
                int pb = wg - 224;
                int mt = wave >> 2, q = wave & 3;
                int b = mt * 16 + rowm;
                int cg = q * 16 + rowm;
                const unsigned short* wtp = WTp2 + (size_t)pb * 49152 + cg * 768;
                const unsigned short* ep_ = et + b * 256;
                const unsigned short* hp_ = hm_old + b * 512;
#pragma unroll
                for (int kt = 0; kt < 24; ++kt) {
                    int ko = kt * 32 + ks * 8;
                    bf16x8 bf = frag_p(wtp + ko);
                    bf16x8 af = (kt < 16) ? frag_c(hp_ + ko) : frag_p(ep_ + ko - 512);
                    acc = __builtin_amdgcn_mfma_f32_16x16x32_bf16(af, bf, acc, 0, 0, 0);
                }
#pragma unroll
                for (int r2 = 0; r2 < 4; ++r2)
                    stgf(p2w + (mt * 16 + (lane >> 4) * 4 + r2) * 512 + pb * 64 + cg, acc[r2]);
            }
        }
        gbar(bar, tid, wg, ++bn);

        // ================= Phase B: attention partials (wg<224) =================
        if (wg < 224) {
            int kB = wg >> 5, it = wg & 31;
            int mt = wave & 1, kq = wave >> 1;
            f32x4 acc = {0.f, 0.f, 0.f, 0.f};
            const unsigned short* wtp = WTp1 + (it * 16 + rowm) * 512;
            const unsigned short* hp_ = hb_new + (kB * 32 + mt * 16 + rowm) * 512;
#pragma unroll
            for (int s4 = 0; s4 < 4; ++s4) {
                int ko = (kq * 4 + s4) * 32 + ks * 8;
                bf16x8 bf = frag_p(wtp + ko);
                bf16x8 af = frag_c(hp_ + ko);
                acc = __builtin_amdgcn_mfma_f32_16x16x32_bf16(af, bf, acc, 0, 0, 0);
            }
            ((f32x4*)smem)[wave * 64 + lane] = acc;
            __syncthreads();
            {
                int b2 = tid >> 4, i2 = tid & 15;
                int mt2 = b2 >> 4, rr = b2 & 15;
                int ln = ((rr & 12) << 2) | i2, rg = rr & 3;
                float val = 0.f;
#pragma unroll
                for (int q2 = 0; q2 < 4; ++q2)
                    val += smem[((q2 * 2 + mt2) * 64 + ln) * 4 + rg];
                val += ldcf(p2w + b2 * 512 + it * 16 + i2);
                float sv = tanhf(val) * Us_w[it * 16 + i2];
                sv += __shfl_xor(sv, 1, 64); sv += __shfl_xor(sv, 2, 64);
                sv += __shfl_xor(sv, 4, 64); sv += __shfl_xor(sv, 8, 64);
                if (i2 == 0) stgf(partial + (kB * 32 + it) * 32 + b2, sv);
            }
        }
        gbar(bar, tid, wg, ++bn);

        // ================= Phase C: softmax + Rt + main gates + cell =============
        {
            int mh = wg >> 7, ntc = wg & 127;  // sharers (mh=0,1) differ by 128 -> same XCD
            unsigned short* Rt = (unsigned short*)smem;  // [16][520] = 16640 B
            float* sredc = smem + 4160;                  // 8*64*4 f32
            float* ssi = smem + 6208;                    // 112
            float* sa  = smem + 6320;                    // 112
            float* sg2 = smem + 6432;                    // 256
            if (tid < 112) {
                int kq = tid % 7, bl = tid / 7;
                float s = 0.f;
                for (int itq = 0; itq < 32; ++itq)
                    s += ldcf(partial + (kq * 32 + itq) * 32 + mh * 16 + bl);
                ssi[bl * 7 + kq] = s;
            }
            __syncthreads();
            if (tid < 16) {
                float mx = -1e30f;
                for (int kq = 0; kq < 7; ++kq) mx = fmaxf(mx, ssi[tid * 7 + kq]);
                float den = 0.f, e[7];
                for (int kq = 0; kq < 7; ++kq) { e[kq] = expf(ssi[tid * 7 + kq] - mx); den += e[kq]; }
                float rd = 1.f / den;
                for (int kq = 0; kq < 7; ++kq) sa[tid * 7 + kq] = e[kq] * rd;
            }
            __syncthreads();
            for (int i = tid; i < 4096; i += 512) {   // Rt build: 16 b x 256 u32-pairs
                int bl = i >> 8, rp = i & 255;
                float a0 = 0.f, a1 = 0.f;
#pragma unroll
                for (int kq = 0; kq < 7; ++kq) {
                    unsigned v = ldc32(hb_new + (kq * 32 + mh * 16 + bl) * 512 + 2 * rp);
                    float w = sa[bl * 7 + kq];
                    a0 = fmaf(w, b2f((unsigned short)v), a0);
                    a1 = fmaf(w, b2f((unsigned short)(v >> 16)), a1);
                }
                Rt[bl * 520 + 2 * rp]     = f2b(a0);
                Rt[bl * 520 + 2 * rp + 1] = f2b(a1);
            }
            __syncthreads();
            f32x4 acc = {0.f, 0.f, 0.f, 0.f};
            const unsigned short* wtp = WTc + (size_t)ntc * 20480 + rowm * 1280;
            int b = mh * 16 + rowm;
            const unsigned short* ep_ = et + b * 256;
            const unsigned short* hp_ = hm_old + b * 512;
            const unsigned short* rp_ = Rt + rowm * 520;
#pragma unroll
            for (int s5 = 0; s5 < 5; ++s5) {
                int kt = wave * 5 + s5;
                int ko = kt * 32 + ks * 8;
                bf16x8 bf = frag_p(wtp + ko);
                bf16x8 af;
                if (kt < 8) af = frag_p(ep_ + ko);
                else if (kt < 24) af = frag_c(hp_ + ko - 256);
                else af = frag_p(rp_ + ko - 768);
                acc = __builtin_amdgcn_mfma_f32_16x16x32_bf16(af, bf, acc, 0, 0, 0);
            }
            ((f32x4*)sredc)[wave * 64 + lane] = acc;
            __syncthreads();
            if (tid < 256) {
                int rr = tid >> 4, c = tid & 15;
                int ln = ((rr & 12) << 2) | c, rg = rr & 3;
                float val = 0.f;
#pragma unroll
                for (int w2 = 0; w2 < 8; ++w2) val += sredc[(w2 * 64 + ln) * 4 + rg];
                sg2[rr * 16 + c] = val;
            }
            __syncthreads();
            if (tid < 64) {
                int bl = tid >> 2, j = tid & 3;
                int b2 = mh * 16 + bl;
                int colh = ntc * 4 + j;
                float gi = sg2[bl * 16 + 0  + j] + b_c[colh];
                float gf = sg2[bl * 16 + 4  + j] + b_c[512 + colh];
                float gg = sg2[bl * 16 + 8  + j] + b_c[1024 + colh];
                float go = sg2[bl * 16 + 12 + j] + b_c[1536 + colh];
                int cidx = b2 * 512 + colh;
                float cold = cmain[cidx];
                float cn = sigm(gf) * cold + sigm(gi) * tanhf(gg);
                float hn = sigm(go) * tanhf(cn);
                cmain[cidx] = cn;
                out[(size_t)b2 * 262144 + (size_t)t * 512 + colh] = hn;
                int hbits = (int)f2b(hn);
                int oth = __shfl_xor(hbits, 1, 64);
                if ((j & 1) == 0)
                    stg32(hm_new + cidx, (unsigned)hbits | ((unsigned)oth << 16));
                if (t == 511) stgf(hNf + cidx, hn);
            }
        }
        gbar(bar, tid, wg, ++bn);
    }

    for (int i = wg * 512 + tid; i < 16384; i += 131072)
        out[8388608 + i] = ldcf(hNf + i);
}

extern "C" void kernel_launch(void* const* d_in, const int* in_sizes, int n_in,
                              void* d_out, int out_size, void* d_ws, size_t ws_size,
                              hipStream_t stream) {
    const int*   x      = (const int*)d_in[0];
    const int*   taskp  = (const int*)d_in[1];
    const float* embed  = (const float*)d_in[2];
    const float* Wx_t   = (const float*)d_in[3];
    const float* Wh_t   = (const float*)d_in[4];
    const float* b_t    = (const float*)d_in[5];
    const float* Ws_p1  = (const float*)d_in[6];
    const float* Ws_p2  = (const float*)d_in[7];
    const float* Us_w   = (const float*)d_in[8];
    const float* Wx_c   = (const float*)d_in[10];
    const float* Wh_c   = (const float*)d_in[11];
    const float* Wm_c   = (const float*)d_in[12];
    const float* b_c    = (const float*)d_in[13];
    float* out = (float*)d_out;

    unsigned short* us = (unsigned short*)d_ws;
    unsigned short* WTa   = us;                       // 11,010,048
    unsigned short* WTp2  = WTa   + 11010048;         //    393,216
    unsigned short* WTp1  = WTp2  + 393216;           //    262,144
    unsigned short* WTc   = WTp1  + 262144;           //  2,621,440
    unsigned short* embbf = WTc   + 2621440;          //  4,194,304
    unsigned short* hbf   = embbf + 4194304;          //    229,376
    unsigned short* hmbf  = hbf   + 229376;           //     32,768
    float* fb      = (float*)(hmbf + 32768);
    float* ctask   = fb;                              //    114,688
    float* cmain   = ctask + 114688;                  //     16,384
    float* p2w     = cmain + 16384;                   //     16,384
    float* partial = p2w   + 16384;                   //      7,168
    float* hNf     = partial + 7168;                  //     16,384
    unsigned* bar  = (unsigned*)(hNf + 16384);        //      4 KiB

    hipMemsetAsync(bar, 0, 4096, stream);

    void* args[] = { (void*)&x, (void*)&taskp, (void*)&embed,
                     (void*)&Wx_t, (void*)&Wh_t, (void*)&b_t,
                     (void*)&Ws_p1, (void*)&Ws_p2, (void*)&Us_w,
                     (void*)&Wx_c, (void*)&Wh_c, (void*)&Wm_c, (void*)&b_c,
                     (void*)&out,
                     (void*)&WTa, (void*)&WTp2, (void*)&WTp1, (void*)&WTc,
                     (void*)&embbf, (void*)&hbf, (void*)&hmbf,
                     (void*)&ctask, (void*)&cmain, (void*)&p2w, (void*)&partial,
                     (void*)&hNf, (void*)&bar };
    hipLaunchCooperativeKernel((void*)fused_all, dim3(256), dim3(512), args, 0, stream);
}

// Round 16
// 13274.263 us; speedup vs baseline: 6.7914x; 1.2148x over previous
//
#include <hip/hip_runtime.h>

#define S_ 512
#define SCOPE __HIP_MEMORY_SCOPE_AGENT

typedef short bf16x8 __attribute__((ext_vector_type(8)));
typedef float f32x4 __attribute__((ext_vector_type(4)));

__device__ __forceinline__ float sigm(float x) { return 1.f / (1.f + expf(-x)); }
__device__ __forceinline__ float b2f(unsigned short u) {
    return __builtin_bit_cast(float, (unsigned)u << 16);
}
__device__ __forceinline__ unsigned short f2b(float f) {
    unsigned x = __builtin_bit_cast(unsigned, f);
    return (unsigned short)((x + 0x7fffu + ((x >> 16) & 1u)) >> 16);
}
__device__ __forceinline__ float ldcf(const float* p) {
    return __hip_atomic_load(p, __ATOMIC_RELAXED, SCOPE);
}
__device__ __forceinline__ unsigned ldc32(const void* p) {
    return __hip_atomic_load((const unsigned*)p, __ATOMIC_RELAXED, SCOPE);
}
__device__ __forceinline__ unsigned long long ldc64(const void* p) {
    return __hip_atomic_load((const unsigned long long*)p, __ATOMIC_RELAXED, SCOPE);
}
__device__ __forceinline__ void stg32(void* p, unsigned v) {
    __hip_atomic_store((unsigned*)p, v, __ATOMIC_RELAXED, SCOPE);
}
__device__ __forceinline__ void stgf(float* p, float v) {
    __hip_atomic_store(p, v, __ATOMIC_RELAXED, SCOPE);
}
// coherent bf16x8 fragment (cross-WG per-step data)
__device__ __forceinline__ bf16x8 frag_c(const unsigned short* p) {
    union { unsigned long long q[2]; bf16x8 v; } u;
    u.q[0] = ldc64(p); u.q[1] = ldc64(p + 4);
    return u.v;
}
// plain bf16x8 fragment (static/L2 data or LDS)
__device__ __forceinline__ bf16x8 frag_p(const unsigned short* p) {
    return *(const bf16x8*)p;
}

// 2-level monotonic grid barrier (validated round 9).
__device__ __forceinline__ void gbar(unsigned* bar, int tid, int wg, unsigned n) {
    __syncthreads();
    if (tid == 0) {
        int g = wg >> 5;
        unsigned* gcnt = bar + 64 + g * 32;
        unsigned* ggen = bar + 320 + g * 32;
        unsigned old = __hip_atomic_fetch_add(gcnt, 1u, __ATOMIC_RELAXED, SCOPE);
        if (old == n * 32u - 1u) {
            unsigned rold = __hip_atomic_fetch_add(bar, 1u, __ATOMIC_RELAXED, SCOPE);
            if (rold == n * 8u - 1u) {
                __hip_atomic_store(bar + 32, n, __ATOMIC_RELAXED, SCOPE);
            } else {
                while (__hip_atomic_load(bar + 32, __ATOMIC_RELAXED, SCOPE) < n)
                    __builtin_amdgcn_s_sleep(1);
            }
            __hip_atomic_store(ggen, n, __ATOMIC_RELAXED, SCOPE);
        } else {
            while (__hip_atomic_load(ggen, __ATOMIC_RELAXED, SCOPE) < n)
                __builtin_amdgcn_s_sleep(1);
        }
        asm volatile("" ::: "memory");
    }
    __syncthreads();
}

__global__ __launch_bounds__(512) void fused_all(
        const int* __restrict__ x, const int* __restrict__ taskp,
        const float* __restrict__ embed,
        const float* __restrict__ Wx_t, const float* __restrict__ Wh_t,
        const float* __restrict__ b_t,
        const float* __restrict__ Ws_p1, const float* __restrict__ Ws_p2,
        const float* __restrict__ Us_w,
        const float* __restrict__ Wx_c, const float* __restrict__ Wh_c,
        const float* __restrict__ Wm_c, const float* __restrict__ b_c,
        float* __restrict__ out,
        unsigned short* __restrict__ WTa,  unsigned short* __restrict__ WTp2,
        unsigned short* __restrict__ WTp1, unsigned short* __restrict__ WTc,
        unsigned short* __restrict__ embbf, unsigned short* __restrict__ hbf,
        unsigned short* __restrict__ hmbf,
        float* __restrict__ ctask, float* __restrict__ cmain,
        float* __restrict__ p2w, float* __restrict__ partial,
        float* __restrict__ hNf, unsigned* __restrict__ bar)
{
    __shared__ float smem[7168];                 // 28,672 B phase scratch
    __shared__ unsigned short swA[64 * 776];     // 99,328 B A/p2 weight slice (pad 768->776)
    const int wg = blockIdx.x, tid = threadIdx.x;
    const int lane = tid & 63, wave = tid >> 6;
    const int rowm = lane & 15, ks = lane >> 4;
    const int task = taskp[0];
    unsigned bn = 0;

    // ================= prologue: zero state + bf16 transposed weight build ======
    for (int i = wg * 512 + tid; i < 114688; i += 131072) stg32((unsigned*)hbf + i, 0u);
    for (int i = wg * 512 + tid; i < 16384; i += 131072) stg32((unsigned*)hmbf + i, 0u);
    for (int i = wg * 512 + tid; i < 114688; i += 131072) stgf(ctask + i, 0.f);
    for (int i = wg * 512 + tid; i < 16384; i += 131072) stgf(cmain + i, 0.f);
    // emb gather -> bf16 [t][b][e]
    for (int i = wg * 512 + tid; i < 2097152; i += 131072) {
        int ts = i >> 12, b = (i >> 7) & 31, ep = i & 127;
        int tok = x[b * S_ + ts];
        const float* s = embed + (size_t)tok * 256 + 2 * ep;
        stg32((unsigned*)embbf + i, (unsigned)f2b(s[0]) | ((unsigned)f2b(s[1]) << 16));
    }
    // WTa[s=(k,nt)][cg64][kr768]: col(cg)=(cg>>4)*512+nt*16+(cg&15); k-rows: Wx|Wh
    for (int i = wg * 512 + tid; i < 5505024; i += 131072) {
        int s = i / 24576, r = i % 24576, kp = r >> 6, cg = r & 63;
        int k = s >> 5, nt = s & 31, kk = k + (k >= task);
        int col = ((cg >> 4) << 9) + nt * 16 + (cg & 15);
        int kr = kp * 2;
        const float* src = (kr < 256)
            ? Wx_t + (size_t)kk * 524288 + (size_t)kr * 2048 + col
            : Wh_t + (size_t)kk * 1048576 + (size_t)(kr - 256) * 2048 + col;
        stg32((unsigned*)WTa + (size_t)s * 24576 + cg * 384 + kp,
              (unsigned)f2b(src[0]) | ((unsigned)f2b(src[2048]) << 16));
    }
    // WTp2[pb][cg64][kr768]
    for (int i = wg * 512 + tid; i < 196608; i += 131072) {
        int p = i / 24576, r = i % 24576, kp = r >> 6, cg = r & 63;
        int col = p * 64 + cg, kr = kp * 2;
        const float* src = Ws_p2 + (size_t)kr * 512 + col;
        stg32((unsigned*)WTp2 + p * 24576 + cg * 384 + kp,
              (unsigned)f2b(src[0]) | ((unsigned)f2b(src[512]) << 16));
    }
    // WTp1 = bf16(Ws_p1) [i][j]
    for (int i = wg * 512 + tid; i < 131072; i += 131072) {
        const float* src = Ws_p1 + 2 * (size_t)i;
        stg32((unsigned*)WTp1 + i, (unsigned)f2b(src[0]) | ((unsigned)f2b(src[1]) << 16));
    }
    // WTc[ntc][cg16][kr1280]: col(cg)=(cg>>2)*512+ntc*4+(cg&3); rows: Wx_c|Wh_c|Wm_c
    for (int i = wg * 512 + tid; i < 1310720; i += 131072) {
        int ntc = i / 10240, r = i % 10240, kp = r >> 4, cg = r & 15;
        int col = ((cg >> 2) << 9) + ntc * 4 + (cg & 3);
        int kr = kp * 2;
        const float* src = (kr < 256) ? Wx_c + (size_t)kr * 2048 + col
                         : (kr < 768) ? Wh_c + (size_t)(kr - 256) * 2048 + col
                                      : Wm_c + (size_t)(kr - 768) * 2048 + col;
        stg32((unsigned*)WTc + ntc * 10240 + cg * 640 + kp,
              (unsigned)f2b(src[0]) | ((unsigned)f2b(src[2048]) << 16));
    }
    gbar(bar, tid, wg, ++bn);

    // stage this WG's A/p2 weight slice into LDS (once; stride 768 -> 776 pad)
    if (wg < 232) {
        const unsigned* srcw = (const unsigned*)(wg < 224
            ? WTa + (size_t)wg * 49152 : WTp2 + (size_t)(wg - 224) * 49152);
        for (int i = tid; i < 24576; i += 512) {
            int cg = i / 384, kp = i % 384;
            ((unsigned*)(swA + cg * 776))[kp] = srcw[cg * 384 + kp];
        }
    }
    __syncthreads();

    // phase-B WG remap: 7 sharers of each WTp1 it-slice land on one XCD
    const int xq = wg & 7, jq = wg >> 3;
    const int kB = jq >> 2, itB = xq + 8 * (jq & 3);

    for (int t = 0; t < S_; ++t) {
        const int old = t & 1, nw = old ^ 1;
        const unsigned short* hb_old = hbf + old * 114688;
        unsigned short* hb_new = hbf + nw * 114688;
        const unsigned short* hm_old = hmbf + old * 16384;
        unsigned short* hm_new = hmbf + nw * 16384;
        const unsigned short* et = embbf + (size_t)t * 8192;

        // ================= Phase A: task gates+cell (wg<224) + p2 (224..231) =====
        if (wg < 232) {
            f32x4 acc = {0.f, 0.f, 0.f, 0.f};
            if (wg < 224) {
                int k = wg >> 5, nt = wg & 31;
                int mt = wave >> 2, g = wave & 3;
                int b = mt * 16 + rowm;
                const unsigned short* wtp = swA + (g * 16 + rowm) * 776;
                const unsigned short* ep_ = et + b * 256;
                const unsigned short* hp_ = hb_old + (k * 32 + b) * 512;
#pragma unroll
                for (int kt = 0; kt < 24; ++kt) {
                    int ko = kt * 32 + ks * 8;
                    bf16x8 bf = frag_p(wtp + ko);
                    bf16x8 af = (kt < 8) ? frag_p(ep_ + ko) : frag_c(hp_ + ko - 256);
                    acc = __builtin_amdgcn_mfma_f32_16x16x32_bf16(af, bf, acc, 0, 0, 0);
                }
                float* sg = smem;
#pragma unroll
                for (int r2 = 0; r2 < 4; ++r2)
                    sg[(mt * 16 + (lane >> 4) * 4 + r2) * 64 + g * 16 + rowm] = acc[r2];
                __syncthreads();
                {
                    int b2 = tid >> 4, hc = tid & 15;
                    int kk = k + (k >= task);
                    const float* bb = b_t + kk * 2048 + nt * 16 + hc;
                    float gi = sg[b2 * 64 + hc]      + bb[0];
                    float gf = sg[b2 * 64 + 16 + hc] + bb[512];
                    float gg = sg[b2 * 64 + 32 + hc] + bb[1024];
                    float go = sg[b2 * 64 + 48 + hc] + bb[1536];
                    int cidx = (k * 32 + b2) * 512 + nt * 16 + hc;
                    float cold = ctask[cidx];
                    float cn = sigm(gf) * cold + sigm(gi) * tanhf(gg);
                    float hn = sigm(go) * tanhf(cn);
                    ctask[cidx] = cn;
                    int hbits = (int)f2b(hn);
                    int oth = __shfl_xor(hbits, 1, 64);
                    if ((hc & 1) == 0)
                        stg32(hb_new + cidx, (unsigned)hbits | ((unsigned)oth << 16));
                }
            } else {
                int pb = wg - 224;
                int mt = wave >> 2, q = wave & 3;
                int b = mt * 16 + rowm;
                int cg = q * 16 + rowm;
                const unsigned short* wtp = swA + cg * 776;
                const unsigned short* ep_ = et + b * 256;
                const unsigned short* hp_ = hm_old + b * 512;
#pragma unroll
                for (int kt = 0; kt < 24; ++kt) {
                    int ko = kt * 32 + ks * 8;
                    bf16x8 bf = frag_p(wtp + ko);
                    bf16x8 af = (kt < 16) ? frag_c(hp_ + ko) : frag_p(ep_ + ko - 512);
                    acc = __builtin_amdgcn_mfma_f32_16x16x32_bf16(af, bf, acc, 0, 0, 0);
                }
#pragma unroll
                for (int r2 = 0; r2 < 4; ++r2)
                    stgf(p2w + (mt * 16 + (lane >> 4) * 4 + r2) * 512 + pb * 64 + cg, acc[r2]);
            }
        }
        gbar(bar, tid, wg, ++bn);

        // ================= Phase B: attention partials (wg<224) =================
        if (wg < 224) {
            int mt = wave & 1, kq = wave >> 1;
            f32x4 acc = {0.f, 0.f, 0.f, 0.f};
            const unsigned short* wtp = WTp1 + (itB * 16 + rowm) * 512;
            const unsigned short* hp_ = hb_new + (kB * 32 + mt * 16 + rowm) * 512;
#pragma unroll
            for (int s4 = 0; s4 < 4; ++s4) {
                int ko = (kq * 4 + s4) * 32 + ks * 8;
                bf16x8 bf = frag_p(wtp + ko);
                bf16x8 af = frag_c(hp_ + ko);
                acc = __builtin_amdgcn_mfma_f32_16x16x32_bf16(af, bf, acc, 0, 0, 0);
            }
            ((f32x4*)smem)[wave * 64 + lane] = acc;
            __syncthreads();
            {
                int b2 = tid >> 4, i2 = tid & 15;
                int mt2 = b2 >> 4, rr = b2 & 15;
                int ln = ((rr & 12) << 2) | i2, rg = rr & 3;
                float val = 0.f;
#pragma unroll
                for (int q2 = 0; q2 < 4; ++q2)
                    val += smem[((q2 * 2 + mt2) * 64 + ln) * 4 + rg];
                val += ldcf(p2w + b2 * 512 + itB * 16 + i2);
                float sv = tanhf(val) * Us_w[itB * 16 + i2];
                sv += __shfl_xor(sv, 1, 64); sv += __shfl_xor(sv, 2, 64);
                sv += __shfl_xor(sv, 4, 64); sv += __shfl_xor(sv, 8, 64);
                if (i2 == 0) stgf(partial + (kB * 32 + itB) * 32 + b2, sv);
            }
        }
        gbar(bar, tid, wg, ++bn);

        // ================= Phase C: softmax + Rt + main gates + cell =============
        {
            int mh = wg >> 7, ntc = wg & 127;  // sharers (mh=0,1) differ by 128 -> same XCD
            unsigned short* Rt = (unsigned short*)smem;  // [16][520] = 16640 B
            float* sredc = smem + 4160;                  // 8*64*4 f32
            float* ssi = smem + 6208;                    // 112
            float* sa  = smem + 6320;                    // 112
            float* sg2 = smem + 6432;                    // 256
            if (tid < 112) {
                int kq = tid % 7, bl = tid / 7;
                float s = 0.f;
                for (int itq = 0; itq < 32; ++itq)
                    s += ldcf(partial + (kq * 32 + itq) * 32 + mh * 16 + bl);
                ssi[bl * 7 + kq] = s;
            }
            __syncthreads();
            if (tid < 16) {
                float mx = -1e30f;
                for (int kq = 0; kq < 7; ++kq) mx = fmaxf(mx, ssi[tid * 7 + kq]);
                float den = 0.f, e[7];
                for (int kq = 0; kq < 7; ++kq) { e[kq] = expf(ssi[tid * 7 + kq] - mx); den += e[kq]; }
                float rd = 1.f / den;
                for (int kq = 0; kq < 7; ++kq) sa[tid * 7 + kq] = e[kq] * rd;
            }
            __syncthreads();
            for (int i = tid; i < 4096; i += 512) {   // Rt build: 16 b x 256 u32-pairs
                int bl = i >> 8, rp = i & 255;
                float a0 = 0.f, a1 = 0.f;
#pragma unroll
                for (int kq = 0; kq < 7; ++kq) {
                    unsigned v = ldc32(hb_new + (kq * 32 + mh * 16 + bl) * 512 + 2 * rp);
                    float w = sa[bl * 7 + kq];
                    a0 = fmaf(w, b2f((unsigned short)v), a0);
                    a1 = fmaf(w, b2f((unsigned short)(v >> 16)), a1);
                }
                Rt[bl * 520 + 2 * rp]     = f2b(a0);
                Rt[bl * 520 + 2 * rp + 1] = f2b(a1);
            }
            __syncthreads();
            f32x4 acc = {0.f, 0.f, 0.f, 0.f};
            const unsigned short* wtp = WTc + (size_t)ntc * 20480 + rowm * 1280;
            int b = mh * 16 + rowm;
            const unsigned short* ep_ = et + b * 256;
            const unsigned short* hp_ = hm_old + b * 512;
            const unsigned short* rp_ = Rt + rowm * 520;
#pragma unroll
            for (int s5 = 0; s5 < 5; ++s5) {
                int kt = wave * 5 + s5;
                int ko = kt * 32 + ks * 8;
                bf16x8 bf = frag_p(wtp + ko);
                bf16x8 af;
                if (kt < 8) af = frag_p(ep_ + ko);
                else if (kt < 24) af = frag_c(hp_ + ko - 256);
                else af = frag_p(rp_ + ko - 768);
                acc = __builtin_amdgcn_mfma_f32_16x16x32_bf16(af, bf, acc, 0, 0, 0);
            }
            __syncthreads();          // all Rt reads done before sredc overwrites smem
            ((f32x4*)sredc)[wave * 64 + lane] = acc;
            __syncthreads();
            if (tid < 256) {
                int rr = tid >> 4, c = tid & 15;
                int ln = ((rr & 12) << 2) | c, rg = rr & 3;
                float val = 0.f;
#pragma unroll
                for (int w2 = 0; w2 < 8; ++w2) val += sredc[(w2 * 64 + ln) * 4 + rg];
                sg2[rr * 16 + c] = val;
            }
            __syncthreads();
            if (tid < 64) {
                int bl = tid >> 2, j = tid & 3;
                int b2 = mh * 16 + bl;
                int colh = ntc * 4 + j;
                float gi = sg2[bl * 16 + 0  + j] + b_c[colh];
                float gf = sg2[bl * 16 + 4  + j] + b_c[512 + colh];
                float gg = sg2[bl * 16 + 8  + j] + b_c[1024 + colh];
                float go = sg2[bl * 16 + 12 + j] + b_c[1536 + colh];
                int cidx = b2 * 512 + colh;
                float cold = cmain[cidx];
                float cn = sigm(gf) * cold + sigm(gi) * tanhf(gg);
                float hn = sigm(go) * tanhf(cn);
                cmain[cidx] = cn;
                out[(size_t)b2 * 262144 + (size_t)t * 512 + colh] = hn;
                int hbits = (int)f2b(hn);
                int oth = __shfl_xor(hbits, 1, 64);
                if ((j & 1) == 0)
                    stg32(hm_new + cidx, (unsigned)hbits | ((unsigned)oth << 16));
                if (t == 511) stgf(hNf + cidx, hn);
            }
        }
        gbar(bar, tid, wg, ++bn);
    }

    for (int i = wg * 512 + tid; i < 16384; i += 131072)
        out[8388608 + i] = ldcf(hNf + i);
}

extern "C" void kernel_launch(void* const* d_in, const int* in_sizes, int n_in,
                              void* d_out, int out_size, void* d_ws, size_t ws_size,
                              hipStream_t stream) {
    const int*   x      = (const int*)d_in[0];
    const int*   taskp  = (const int*)d_in[1];
    const float* embed  = (const float*)d_in[2];
    const float* Wx_t   = (const float*)d_in[3];
    const float* Wh_t   = (const float*)d_in[4];
    const float* b_t    = (const float*)d_in[5];
    const float* Ws_p1  = (const float*)d_in[6];
    const float* Ws_p2  = (const float*)d_in[7];
    const float* Us_w   = (const float*)d_in[8];
    const float* Wx_c   = (const float*)d_in[10];
    const float* Wh_c   = (const float*)d_in[11];
    const float* Wm_c   = (const float*)d_in[12];
    const float* b_c    = (const float*)d_in[13];
    float* out = (float*)d_out;

    unsigned short* us = (unsigned short*)d_ws;
    unsigned short* WTa   = us;                       // 11,010,048
    unsigned short* WTp2  = WTa   + 11010048;         //    393,216
    unsigned short* WTp1  = WTp2  + 393216;           //    262,144
    unsigned short* WTc   = WTp1  + 262144;           //  2,621,440
    unsigned short* embbf = WTc   + 2621440;          //  4,194,304
    unsigned short* hbf   = embbf + 4194304;          //    229,376
    unsigned short* hmbf  = hbf   + 229376;           //     32,768
    float* fb      = (float*)(hmbf + 32768);
    float* ctask   = fb;                              //    114,688
    float* cmain   = ctask + 114688;                  //     16,384
    float* p2w     = cmain + 16384;                   //     16,384
    float* partial = p2w   + 16384;                   //      7,168
    float* hNf     = partial + 7168;                  //     16,384
    unsigned* bar  = (unsigned*)(hNf + 16384);        //      4 KiB

    hipMemsetAsync(bar, 0, 4096, stream);

    void* args[] = { (void*)&x, (void*)&taskp, (void*)&embed,
                     (void*)&Wx_t, (void*)&Wh_t, (void*)&b_t,
                     (void*)&Ws_p1, (void*)&Ws_p2, (void*)&Us_w,
                     (void*)&Wx_c, (void*)&Wh_c, (void*)&Wm_c, (void*)&b_c,
                     (void*)&out,
                     (void*)&WTa, (void*)&WTp2, (void*)&WTp1, (void*)&WTc,
                     (void*)&embbf, (void*)&hbf, (void*)&hmbf,
                     (void*)&ctask, (void*)&cmain, (void*)&p2w, (void*)&partial,
                     (void*)&hNf, (void*)&bar };
    hipLaunchCooperativeKernel((void*)fused_all, dim3(256), dim3(512), args, 0, stream);
}